// Round 1
// baseline (189.312 us; speedup 1.0000x reference)
//
#include <hip/hip_runtime.h>

// DisMaxLossFirstPart: logits = -|ds|*(dist + mean_c(dist)) / temp
// dist[b,c] = sqrt(max(1 - <fn_b, pn_c>, 0)), fn/pn L2-normalized rows.
// B=32768, C=1000, F=256. fp32 in/out; bf16 MFMA internally.
//
// Round 4: 32 feature rows per block (2 row-groups per wave). Each prototype
// fragment load now feeds TWO independent MFMA chains -> 2x arithmetic
// intensity on the L2 prototype stream (1.05 GB -> 0.52 GB) and 2x ILP per
// wave. VGPR ~180 -> __launch_bounds__(256,2). Everything else (permuted
// proto layout, fp16-packed dist strips, coalesced float4 epilogue) kept.

typedef __attribute__((ext_vector_type(8))) short short8;
typedef __attribute__((ext_vector_type(4))) float f32x4;
typedef __fp16 h2 __attribute__((ext_vector_type(2)));   // matches cvt_pkrtz return

union U16 { uint4 u4; short8 s8; };

static __device__ __forceinline__ unsigned short f2bf(float x){
  union { float f; unsigned u; } v; v.f = x;
  unsigned r = v.u + 0x7fffu + ((v.u >> 16) & 1u);   // RNE
  return (unsigned short)(r >> 16);
}

#define CPAD 1024          // prototype rows padded to 1024

// Normalize prototypes [C x 256] fp32 -> bf16 in fragment-ready permuted
// layout: 16B chunk index (t*8 + s)*64 + quad*16 + l16 holds
// pn[t*16 + l16][quad*8 + s*32 .. +8]. Rows >= C written as zeros.
__global__ void norm_protos_kernel(const float* __restrict__ src,
                                   unsigned short* __restrict__ dst, int C)
{
  const int wave = threadIdx.x >> 6;
  const int lane = threadIdx.x & 63;
  const int row  = blockIdx.x * 4 + wave;     // 0..1023
  const int t    = row >> 4;
  const int l16  = row & 15;
  const int s    = lane >> 3;                 // element e=4l: s = e>>5
  const int quad = (lane >> 1) & 3;           // quad = (e>>3)&3
  const int j    = (lane & 1) * 4;            // j = e&7 in {0,4}

  ushort4 o = {0, 0, 0, 0};
  if (row < C){
    const float4 v = *(const float4*)(src + row * 256 + lane * 4);
    float ss = v.x*v.x + v.y*v.y + v.z*v.z + v.w*v.w;
    #pragma unroll
    for (int off = 32; off; off >>= 1) ss += __shfl_xor(ss, off);
    const float inv = 1.0f / fmaxf(sqrtf(ss), 1e-12f);
    o.x = f2bf(v.x * inv); o.y = f2bf(v.y * inv);
    o.z = f2bf(v.z * inv); o.w = f2bf(v.w * inv);
  }
  *(ushort4*)(dst + ((size_t)((t*8 + s)*64 + quad*16 + l16))*8 + j) = o;
}

__global__ __launch_bounds__(256, 2)
void fused_kernel(const float* __restrict__ feats,
                  const unsigned short* __restrict__ pnw,
                  const float* __restrict__ ds,
                  const float* __restrict__ temp,
                  float* __restrict__ out, int C)
{
  __shared__ float wsum[2][16][4];   // [row-group][feature-row l16][wave]

  const int tid  = threadIdx.x;
  const int wave = tid >> 6;
  const int lane = tid & 63;
  const int quad = lane >> 4;
  const int l16  = lane & 15;
  const long rowbase = (long)blockIdx.x * 32;

  // ---- Phase 0: B-fragments (features) for 2 row-groups, norm fused ----
  // ffrag[rg][s] = bf16( fn[rowbase+rg*16+l16][quad*8 + s*32 .. +8] )
  short8 ffrag[2][8];
  #pragma unroll
  for (int rg = 0; rg < 2; ++rg){
    const float* rp = feats + (rowbase + rg*16 + l16) * 256 + quad*8;
    float4 va[8], vb[8];
    float ss = 0.f;
    #pragma unroll
    for (int s = 0; s < 8; ++s){
      va[s] = *(const float4*)(rp + s*32);
      vb[s] = *(const float4*)(rp + s*32 + 4);
      ss += va[s].x*va[s].x + va[s].y*va[s].y + va[s].z*va[s].z + va[s].w*va[s].w;
      ss += vb[s].x*vb[s].x + vb[s].y*vb[s].y + vb[s].z*vb[s].z + vb[s].w*vb[s].w;
    }
    ss += __shfl_xor(ss, 16);
    ss += __shfl_xor(ss, 32);
    const float inv = __builtin_amdgcn_rcpf(__builtin_amdgcn_sqrtf(fmaxf(ss, 1e-24f)));
    #pragma unroll
    for (int s = 0; s < 8; ++s){
      U16 u;
      u.u4.x = (unsigned)f2bf(va[s].x*inv) | ((unsigned)f2bf(va[s].y*inv) << 16);
      u.u4.y = (unsigned)f2bf(va[s].z*inv) | ((unsigned)f2bf(va[s].w*inv) << 16);
      u.u4.z = (unsigned)f2bf(vb[s].x*inv) | ((unsigned)f2bf(vb[s].y*inv) << 16);
      u.u4.w = (unsigned)f2bf(vb[s].z*inv) | ((unsigned)f2bf(vb[s].w*inv) << 16);
      ffrag[rg][s] = u.s8;
    }
  }

  // ---- Single GEMM pass: wave owns classes [wave*256, +256) in 16 tiles,
  //      each prototype fragment feeds BOTH row-groups ----
  const uint4* tp = (const uint4*)pnw + (size_t)(wave*16)*512 + lane;

  h2 dd0[16][2];     // per-lane dist strip rg0, fp16-packed (32 VGPRs)
  h2 dd1[16][2];     // per-lane dist strip rg1
  float rsum0 = 0.f, rsum1 = 0.f;

  #pragma unroll
  for (int wt = 0; wt < 16; ++wt){
    const uint4* bp = tp + (size_t)wt*512;
    short8 pfrag[8];
    #pragma unroll
    for (int s = 0; s < 8; ++s){ U16 u; u.u4 = bp[s*64]; pfrag[s] = u.s8; }

    f32x4 acc0 = (f32x4){0.f, 0.f, 0.f, 0.f};
    f32x4 acc1 = (f32x4){0.f, 0.f, 0.f, 0.f};
    #pragma unroll
    for (int s = 0; s < 8; ++s){
      acc0 = __builtin_amdgcn_mfma_f32_16x16x32_bf16(pfrag[s], ffrag[0][s], acc0, 0, 0, 0);
      acc1 = __builtin_amdgcn_mfma_f32_16x16x32_bf16(pfrag[s], ffrag[1][s], acc1, 0, 0, 0);
    }

    float a0 = __builtin_amdgcn_sqrtf(fmaxf(1.0f - acc0[0], 0.0f));
    float a1 = __builtin_amdgcn_sqrtf(fmaxf(1.0f - acc0[1], 0.0f));
    float a2 = __builtin_amdgcn_sqrtf(fmaxf(1.0f - acc0[2], 0.0f));
    float a3 = __builtin_amdgcn_sqrtf(fmaxf(1.0f - acc0[3], 0.0f));
    float b0 = __builtin_amdgcn_sqrtf(fmaxf(1.0f - acc1[0], 0.0f));
    float b1 = __builtin_amdgcn_sqrtf(fmaxf(1.0f - acc1[1], 0.0f));
    float b2 = __builtin_amdgcn_sqrtf(fmaxf(1.0f - acc1[2], 0.0f));
    float b3 = __builtin_amdgcn_sqrtf(fmaxf(1.0f - acc1[3], 0.0f));

    const int cls = wave*256 + wt*16 + quad*4;   // C%4==0: all-or-nothing
    rsum0 += (cls < C) ? (a0 + a1 + a2 + a3) : 0.0f;
    rsum1 += (cls < C) ? (b0 + b1 + b2 + b3) : 0.0f;

    dd0[wt][0] = __builtin_amdgcn_cvt_pkrtz(a0, a1);
    dd0[wt][1] = __builtin_amdgcn_cvt_pkrtz(a2, a3);
    dd1[wt][0] = __builtin_amdgcn_cvt_pkrtz(b0, b1);
    dd1[wt][1] = __builtin_amdgcn_cvt_pkrtz(b2, b3);
  }

  // ---- Row means: reduce over quads, exchange across waves ----
  rsum0 += __shfl_xor(rsum0, 16);
  rsum0 += __shfl_xor(rsum0, 32);
  rsum1 += __shfl_xor(rsum1, 16);
  rsum1 += __shfl_xor(rsum1, 32);
  if (quad == 0){
    wsum[0][l16][wave] = rsum0;
    wsum[1][l16][wave] = rsum1;
  }
  __syncthreads();

  const float nscale = -fabsf(ds[0]) / temp[0];
  const float4 w0 = *(const float4*)&wsum[0][l16][0];
  const float4 w1 = *(const float4*)&wsum[1][l16][0];
  const float bias0 = nscale * ((w0.x + w0.y + w0.z + w0.w) / (float)C);
  const float bias1 = nscale * ((w1.x + w1.y + w1.z + w1.w) / (float)C);

  // ---- Epilogue: coalesced float4 stores, 2 rows per lane ----
  float* orow0 = out + (rowbase + l16) * (size_t)C;
  float* orow1 = out + (rowbase + 16 + l16) * (size_t)C;
  #pragma unroll
  for (int wt = 0; wt < 16; ++wt){
    const int cls = wave*256 + wt*16 + quad*4;
    if (cls < C){
      float4 o0, o1;
      o0.x = fmaf(nscale, (float)dd0[wt][0][0], bias0);
      o0.y = fmaf(nscale, (float)dd0[wt][0][1], bias0);
      o0.z = fmaf(nscale, (float)dd0[wt][1][0], bias0);
      o0.w = fmaf(nscale, (float)dd0[wt][1][1], bias0);
      o1.x = fmaf(nscale, (float)dd1[wt][0][0], bias1);
      o1.y = fmaf(nscale, (float)dd1[wt][0][1], bias1);
      o1.z = fmaf(nscale, (float)dd1[wt][1][0], bias1);
      o1.w = fmaf(nscale, (float)dd1[wt][1][1], bias1);
      *(float4*)(orow0 + cls) = o0;
      *(float4*)(orow1 + cls) = o1;
    }
  }
}

extern "C" void kernel_launch(void* const* d_in, const int* in_sizes, int n_in,
                              void* d_out, int out_size, void* d_ws, size_t ws_size,
                              hipStream_t stream) {
  const float* features = (const float*)d_in[0];
  const float* protos   = (const float*)d_in[1];
  const float* dscale   = (const float*)d_in[2];
  const float* temp     = (const float*)d_in[3];
  float* out = (float*)d_out;

  const int F = 256;
  const int B = in_sizes[0] / F;   // 32768
  const int C = in_sizes[1] / F;   // 1000

  unsigned short* pnw = (unsigned short*)d_ws;   // [1024 x 256] bf16, permuted

  norm_protos_kernel<<<CPAD/4, 256, 0, stream>>>(protos, pnw, C);
  fused_kernel<<<B/32, 256, 0, stream>>>(features, pnw, dscale, temp, out, C);
}

// Round 2
// 185.249 us; speedup vs baseline: 1.0219x; 1.0219x over previous
//
#include <hip/hip_runtime.h>

// DisMaxLossFirstPart: logits = -|ds|*(dist + mean_c(dist)) / temp
// dist[b,c] = sqrt(max(1 - <fn_b, pn_c>, 0)), fn/pn L2-normalized rows.
// B=32768, C=1000, F=256. fp32 in/out; bf16 MFMA internally.
//
// Round 5: latency-hiding pass. Round 4 (2x intensity) only bought -9% =>
// L2 *bandwidth* is not the bound; exposed L2 *latency* per prototype tile is.
// Changes:
//  - dist strips (both row-groups) spill to LDS (self-addressed, no x-lane):
//    frees 64 VGPRs. 64.5 KB LDS/block -> still 2 blocks/CU.
//  - explicit depth-2 prototype prefetch: 3 rotating 32-VGPR buffers, all
//    indices compile-time via full unroll -> 2 tiles of loads in flight under
//    each tile's MFMA cluster.
//  - s_setprio(1) around MFMA cluster (independent-wave structure).

typedef __attribute__((ext_vector_type(8))) short short8;
typedef __attribute__((ext_vector_type(4))) float f32x4;
typedef __fp16 h2 __attribute__((ext_vector_type(2)));   // matches cvt_pkrtz return

union U16 { uint4 u4; short8 s8; };
union H2U { h2 h; unsigned u; };

static __device__ __forceinline__ unsigned short f2bf(float x){
  union { float f; unsigned u; } v; v.f = x;
  unsigned r = v.u + 0x7fffu + ((v.u >> 16) & 1u);   // RNE
  return (unsigned short)(r >> 16);
}

#define CPAD 1024          // prototype rows padded to 1024

// Normalize prototypes [C x 256] fp32 -> bf16 in fragment-ready permuted
// layout: 16B chunk index (t*8 + s)*64 + quad*16 + l16 holds
// pn[t*16 + l16][quad*8 + s*32 .. +8]. Rows >= C written as zeros.
__global__ void norm_protos_kernel(const float* __restrict__ src,
                                   unsigned short* __restrict__ dst, int C)
{
  const int wave = threadIdx.x >> 6;
  const int lane = threadIdx.x & 63;
  const int row  = blockIdx.x * 4 + wave;     // 0..1023
  const int t    = row >> 4;
  const int l16  = row & 15;
  const int s    = lane >> 3;                 // element e=4l: s = e>>5
  const int quad = (lane >> 1) & 3;           // quad = (e>>3)&3
  const int j    = (lane & 1) * 4;            // j = e&7 in {0,4}

  ushort4 o = {0, 0, 0, 0};
  if (row < C){
    const float4 v = *(const float4*)(src + row * 256 + lane * 4);
    float ss = v.x*v.x + v.y*v.y + v.z*v.z + v.w*v.w;
    #pragma unroll
    for (int off = 32; off; off >>= 1) ss += __shfl_xor(ss, off);
    const float inv = 1.0f / fmaxf(sqrtf(ss), 1e-12f);
    o.x = f2bf(v.x * inv); o.y = f2bf(v.y * inv);
    o.z = f2bf(v.z * inv); o.w = f2bf(v.w * inv);
  }
  *(ushort4*)(dst + ((size_t)((t*8 + s)*64 + quad*16 + l16))*8 + j) = o;
}

__global__ __launch_bounds__(256, 2)
void fused_kernel(const float* __restrict__ feats,
                  const unsigned short* __restrict__ pnw,
                  const float* __restrict__ ds,
                  const float* __restrict__ temp,
                  float* __restrict__ out, int C)
{
  // dist spill buffer: [wave][tile][lane] x 16B (rg0 pair, rg0 pair, rg1, rg1)
  __shared__ uint4 ddbuf[4 * 16 * 64];      // 64 KB
  __shared__ float wsum[2][16][4];          // [row-group][feature-row l16][wave]

  const int tid  = threadIdx.x;
  const int wave = tid >> 6;
  const int lane = tid & 63;
  const int quad = lane >> 4;
  const int l16  = lane & 15;
  const long rowbase = (long)blockIdx.x * 32;

  // ---- Phase 0: B-fragments (features) for 2 row-groups, norm fused ----
  // ffrag[rg][s] = bf16( fn[rowbase+rg*16+l16][quad*8 + s*32 .. +8] )
  short8 ffrag[2][8];
  #pragma unroll
  for (int rg = 0; rg < 2; ++rg){
    const float* rp = feats + (rowbase + rg*16 + l16) * 256 + quad*8;
    float4 va[8], vb[8];
    float ss = 0.f;
    #pragma unroll
    for (int s = 0; s < 8; ++s){
      va[s] = *(const float4*)(rp + s*32);
      vb[s] = *(const float4*)(rp + s*32 + 4);
      ss += va[s].x*va[s].x + va[s].y*va[s].y + va[s].z*va[s].z + va[s].w*va[s].w;
      ss += vb[s].x*vb[s].x + vb[s].y*vb[s].y + vb[s].z*vb[s].z + vb[s].w*vb[s].w;
    }
    ss += __shfl_xor(ss, 16);
    ss += __shfl_xor(ss, 32);
    const float inv = __builtin_amdgcn_rcpf(__builtin_amdgcn_sqrtf(fmaxf(ss, 1e-24f)));
    #pragma unroll
    for (int s = 0; s < 8; ++s){
      U16 u;
      u.u4.x = (unsigned)f2bf(va[s].x*inv) | ((unsigned)f2bf(va[s].y*inv) << 16);
      u.u4.y = (unsigned)f2bf(va[s].z*inv) | ((unsigned)f2bf(va[s].w*inv) << 16);
      u.u4.z = (unsigned)f2bf(vb[s].x*inv) | ((unsigned)f2bf(vb[s].y*inv) << 16);
      u.u4.w = (unsigned)f2bf(vb[s].z*inv) | ((unsigned)f2bf(vb[s].w*inv) << 16);
      ffrag[rg][s] = u.s8;
    }
  }

  // ---- Single GEMM pass: wave owns classes [wave*256, +256) in 16 tiles.
  //      Depth-2 prefetch: 3 rotating prototype buffers, static indices. ----
  const uint4* tp = (const uint4*)pnw + (size_t)(wave*16)*512 + lane;

  U16 buf[3][8];
  #pragma unroll
  for (int s = 0; s < 8; ++s) buf[0][s].u4 = tp[s*64];
  #pragma unroll
  for (int s = 0; s < 8; ++s) buf[1][s].u4 = tp[512 + s*64];

  float rsum0 = 0.f, rsum1 = 0.f;

  #pragma unroll
  for (int wt = 0; wt < 16; ++wt){
    // prefetch tile wt+2 into the free rotating buffer
    if (wt + 2 < 16){
      const uint4* np = tp + (size_t)(wt + 2)*512;
      #pragma unroll
      for (int s = 0; s < 8; ++s) buf[(wt + 2) % 3][s].u4 = np[s*64];
    }

    f32x4 acc0 = (f32x4){0.f, 0.f, 0.f, 0.f};
    f32x4 acc1 = (f32x4){0.f, 0.f, 0.f, 0.f};
    __builtin_amdgcn_s_setprio(1);
    #pragma unroll
    for (int s = 0; s < 8; ++s){
      acc0 = __builtin_amdgcn_mfma_f32_16x16x32_bf16(buf[wt % 3][s].s8, ffrag[0][s], acc0, 0, 0, 0);
      acc1 = __builtin_amdgcn_mfma_f32_16x16x32_bf16(buf[wt % 3][s].s8, ffrag[1][s], acc1, 0, 0, 0);
    }
    __builtin_amdgcn_s_setprio(0);

    float a0 = __builtin_amdgcn_sqrtf(fmaxf(1.0f - acc0[0], 0.0f));
    float a1 = __builtin_amdgcn_sqrtf(fmaxf(1.0f - acc0[1], 0.0f));
    float a2 = __builtin_amdgcn_sqrtf(fmaxf(1.0f - acc0[2], 0.0f));
    float a3 = __builtin_amdgcn_sqrtf(fmaxf(1.0f - acc0[3], 0.0f));
    float b0 = __builtin_amdgcn_sqrtf(fmaxf(1.0f - acc1[0], 0.0f));
    float b1 = __builtin_amdgcn_sqrtf(fmaxf(1.0f - acc1[1], 0.0f));
    float b2 = __builtin_amdgcn_sqrtf(fmaxf(1.0f - acc1[2], 0.0f));
    float b3 = __builtin_amdgcn_sqrtf(fmaxf(1.0f - acc1[3], 0.0f));

    const int cls = wave*256 + wt*16 + quad*4;   // C%4==0: all-or-nothing
    rsum0 += (cls < C) ? (a0 + a1 + a2 + a3) : 0.0f;
    rsum1 += (cls < C) ? (b0 + b1 + b2 + b3) : 0.0f;

    H2U p0, p1, p2, p3;
    p0.h = __builtin_amdgcn_cvt_pkrtz(a0, a1);
    p1.h = __builtin_amdgcn_cvt_pkrtz(a2, a3);
    p2.h = __builtin_amdgcn_cvt_pkrtz(b0, b1);
    p3.h = __builtin_amdgcn_cvt_pkrtz(b2, b3);
    uint4 pk; pk.x = p0.u; pk.y = p1.u; pk.z = p2.u; pk.w = p3.u;
    ddbuf[(wave*16 + wt)*64 + lane] = pk;     // self-addressed spill
  }

  // ---- Row means: reduce over quads, exchange across waves ----
  rsum0 += __shfl_xor(rsum0, 16);
  rsum0 += __shfl_xor(rsum0, 32);
  rsum1 += __shfl_xor(rsum1, 16);
  rsum1 += __shfl_xor(rsum1, 32);
  if (quad == 0){
    wsum[0][l16][wave] = rsum0;
    wsum[1][l16][wave] = rsum1;
  }
  __syncthreads();

  const float nscale = -fabsf(ds[0]) / temp[0];
  const float4 w0 = *(const float4*)&wsum[0][l16][0];
  const float4 w1 = *(const float4*)&wsum[1][l16][0];
  const float bias0 = nscale * ((w0.x + w0.y + w0.z + w0.w) / (float)C);
  const float bias1 = nscale * ((w1.x + w1.y + w1.z + w1.w) / (float)C);

  // ---- Epilogue: read back own strips, coalesced float4 stores ----
  float* orow0 = out + (rowbase + l16) * (size_t)C;
  float* orow1 = out + (rowbase + 16 + l16) * (size_t)C;
  #pragma unroll
  for (int wt = 0; wt < 16; ++wt){
    const int cls = wave*256 + wt*16 + quad*4;
    if (cls < C){
      const uint4 pk = ddbuf[(wave*16 + wt)*64 + lane];
      H2U p0, p1, p2, p3;
      p0.u = pk.x; p1.u = pk.y; p2.u = pk.z; p3.u = pk.w;
      float4 o0, o1;
      o0.x = fmaf(nscale, (float)p0.h[0], bias0);
      o0.y = fmaf(nscale, (float)p0.h[1], bias0);
      o0.z = fmaf(nscale, (float)p1.h[0], bias0);
      o0.w = fmaf(nscale, (float)p1.h[1], bias0);
      o1.x = fmaf(nscale, (float)p2.h[0], bias1);
      o1.y = fmaf(nscale, (float)p2.h[1], bias1);
      o1.z = fmaf(nscale, (float)p3.h[0], bias1);
      o1.w = fmaf(nscale, (float)p3.h[1], bias1);
      *(float4*)(orow0 + cls) = o0;
      *(float4*)(orow1 + cls) = o1;
    }
  }
}

extern "C" void kernel_launch(void* const* d_in, const int* in_sizes, int n_in,
                              void* d_out, int out_size, void* d_ws, size_t ws_size,
                              hipStream_t stream) {
  const float* features = (const float*)d_in[0];
  const float* protos   = (const float*)d_in[1];
  const float* dscale   = (const float*)d_in[2];
  const float* temp     = (const float*)d_in[3];
  float* out = (float*)d_out;

  const int F = 256;
  const int B = in_sizes[0] / F;   // 32768
  const int C = in_sizes[1] / F;   // 1000

  unsigned short* pnw = (unsigned short*)d_ws;   // [1024 x 256] bf16, permuted

  norm_protos_kernel<<<CPAD/4, 256, 0, stream>>>(protos, pnw, C);
  fused_kernel<<<B/32, 256, 0, stream>>>(features, pnw, dscale, temp, out, C);
}